// Round 1
// baseline (1600.866 us; speedup 1.0000x reference)
//
#include <hip/hip_runtime.h>
#include <math.h>

// Quantized causal attention, fp32 baseline.
// S=2048 B=2 H=16 D=128 G=16. Two-pass flash structure:
//   pass 1: QK^T tiles -> online per-row (max, sum_exp, min)
//   pass 2: recompute QK^T tiles -> prob -> int8 requant (pd) -> PV accumulate
// pmin==0 for all causal rows s<S-1 (masked probs are exactly 0.0f), so masked
// entries contribute pd==0 and are skipped; row S-1 uses exp(smin-smax)/denom.

#define S_LEN 2048
#define BATCH 2
#define NH    16
#define HD    128
#define TQ    64
#define TK    64
#define LSTR  129   // LDS row stride (128 + 1) -> conflict-free patterns
#define PSTR  65    // pd tile stride (64 + 1)
#define NTHREADS 256

__global__ __launch_bounds__(NTHREADS) void attn_q_kernel(
    const float* __restrict__ Q, const float* __restrict__ K, const float* __restrict__ V,
    const float* __restrict__ QMIN, const float* __restrict__ QSCALE,
    const float* __restrict__ KMIN, const float* __restrict__ KSCALE,
    const float* __restrict__ VMIN, const float* __restrict__ VSCALE,
    const int* __restrict__ CAUSAL, float* __restrict__ OUT)
{
    __shared__ float qd[TQ * LSTR];
    __shared__ float kd[TK * LSTR];
    __shared__ float vd[TK * LSTR];
    __shared__ float pdl[TQ * PSTR];
    __shared__ float rs_max[TQ], rs_den[TQ], rs_min[TQ];
    __shared__ float rs_invden[TQ], rs_pmin[TQ], rs_psc[TQ], rs_ipsc[TQ];

    const int tid = threadIdx.x;
    const int tx  = tid & 15;       // QK: k-col group / PV: d-col group
    const int ty  = tid >> 4;       // q-row group
    const int bh  = blockIdx.x & (BATCH*NH - 1);
    const int qt  = (S_LEN/TQ - 1) - (int)(blockIdx.x >> 5);  // heavy tiles first
    const int b   = bh >> 4;
    const int h   = bh & 15;
    const int causal = *CAUSAL;
    const int s0  = qt * TQ;
    const int boff = b*(NH*HD) + h*HD;          // 2048*b + 128*h
    const int rstride = BATCH*NH*HD;            // 4096 floats between seq positions
    const float SCALE = 0.08838834764831845f;   // 1/sqrt(128)

    // ---- stage + dequant Q tile ----
    #pragma unroll
    for (int r = 0; r < 8; ++r) {
        int idx = tid + r*NTHREADS;
        int row = idx >> 5;
        int d4  = (idx & 31) << 2;
        int s   = s0 + row;
        float4 x = *reinterpret_cast<const float4*>(Q + (size_t)s*rstride + boff + d4);
        int si = s*(BATCH*NH) + b*NH + h;
        float a = QSCALE[si], c = QMIN[si];
        float* dst = &qd[row*LSTR + d4];
        dst[0] = fmaf(x.x,a,c); dst[1] = fmaf(x.y,a,c);
        dst[2] = fmaf(x.z,a,c); dst[3] = fmaf(x.w,a,c);
    }

    const int kt_end = causal ? qt : (S_LEN/TK - 1);

    float m[4], l[4], mn[4];
    #pragma unroll
    for (int i = 0; i < 4; ++i) { m[i] = -INFINITY; l[i] = 0.0f; mn[i] = INFINITY; }

    // ================= Phase 1: per-row softmax stats =================
    for (int kt = 0; kt <= kt_end; ++kt) {
        const int t0 = kt * TK;
        __syncthreads();
        #pragma unroll
        for (int r = 0; r < 8; ++r) {
            int idx = tid + r*NTHREADS;
            int row = idx >> 5;
            int d4  = (idx & 31) << 2;
            int t   = t0 + row;
            float4 x = *reinterpret_cast<const float4*>(K + (size_t)t*rstride + boff + d4);
            int si = t*(BATCH*NH) + b*NH + h;
            float a = KSCALE[si], c = KMIN[si];
            float* dst = &kd[row*LSTR + d4];
            dst[0] = fmaf(x.x,a,c); dst[1] = fmaf(x.y,a,c);
            dst[2] = fmaf(x.z,a,c); dst[3] = fmaf(x.w,a,c);
        }
        __syncthreads();

        float sc[4][4];
        #pragma unroll
        for (int i=0;i<4;++i)
            #pragma unroll
            for (int j=0;j<4;++j) sc[i][j] = 0.0f;
        #pragma unroll 4
        for (int d = 0; d < HD; ++d) {
            float av[4], bv[4];
            #pragma unroll
            for (int i=0;i<4;++i) av[i] = qd[(4*ty+i)*LSTR + d];
            #pragma unroll
            for (int j=0;j<4;++j) bv[j] = kd[(4*tx+j)*LSTR + d];
            #pragma unroll
            for (int i=0;i<4;++i)
                #pragma unroll
                for (int j=0;j<4;++j)
                    sc[i][j] = fmaf(av[i], bv[j], sc[i][j]);
        }

        const bool dmask = (causal != 0) && (kt == qt);
        #pragma unroll
        for (int i=0;i<4;++i) {
            const int s = s0 + 4*ty + i;
            float sv[4]; float tmax = -INFINITY, tmin = INFINITY;
            #pragma unroll
            for (int j=0;j<4;++j) {
                sv[j] = sc[i][j]*SCALE;
                bool msk = dmask && (t0 + 4*tx + j > s);
                if (msk) sv[j] = -INFINITY;
                else { tmax = fmaxf(tmax, sv[j]); tmin = fminf(tmin, sv[j]); }
            }
            float mm = fmaxf(m[i], tmax);
            if (mm > -INFINITY) {
                float acc = l[i]*expf(m[i]-mm);   // expf(-inf)=0 handles l==0 start
                #pragma unroll
                for (int j=0;j<4;++j) acc += expf(sv[j]-mm); // masked -> expf(-inf)=0
                l[i] = acc; m[i] = mm;
            }
            mn[i] = fminf(mn[i], tmin);
        }
    }

    // reduce (m,l,mn) across the 16 tx-lanes sharing each q row
    #pragma unroll
    for (int i=0;i<4;++i) {
        #pragma unroll
        for (int off = 1; off < 16; off <<= 1) {
            float m2 = __shfl_xor(m[i],  off);
            float l2 = __shfl_xor(l[i],  off);
            float n2 = __shfl_xor(mn[i], off);
            float mm = fmaxf(m[i], m2);
            if (mm > -INFINITY) l[i] = l[i]*expf(m[i]-mm) + l2*expf(m2-mm);
            m[i]  = mm;
            mn[i] = fminf(mn[i], n2);
        }
        if (tx == 0) { rs_max[4*ty+i] = m[i]; rs_den[4*ty+i] = l[i]; rs_min[4*ty+i] = mn[i]; }
    }
    __syncthreads();
    if (tid < TQ) {
        int s = s0 + tid;
        float mx = rs_max[tid], den = rs_den[tid], mnv = rs_min[tid];
        float pmax = 1.0f/den;                       // prob at argmax is exp(0)/den
        bool hasmask = (causal != 0) && (s < S_LEN-1);
        float pmin = hasmask ? 0.0f : expf(mnv - mx)/den;
        float psc  = (pmax - pmin)/255.0f + 1e-12f;
        rs_invden[tid] = 1.0f/den;
        rs_pmin[tid] = pmin;
        rs_psc[tid]  = psc;
        rs_ipsc[tid] = 1.0f/psc;
    }

    // ================= Phase 2: requant + PV =================
    float acc[4][8];
    #pragma unroll
    for (int i=0;i<4;++i)
        #pragma unroll
        for (int jj=0;jj<8;++jj) acc[i][jj] = 0.0f;

    for (int kt = 0; kt <= kt_end; ++kt) {
        const int t0 = kt * TK;
        __syncthreads();   // previous PV done before overwriting kd/vd/pdl
        #pragma unroll
        for (int r = 0; r < 8; ++r) {
            int idx = tid + r*NTHREADS;
            int row = idx >> 5;
            int d4  = (idx & 31) << 2;
            int t   = t0 + row;
            int si  = t*(BATCH*NH) + b*NH + h;
            float4 x = *reinterpret_cast<const float4*>(K + (size_t)t*rstride + boff + d4);
            float a = KSCALE[si], c = KMIN[si];
            float* dst = &kd[row*LSTR + d4];
            dst[0] = fmaf(x.x,a,c); dst[1] = fmaf(x.y,a,c);
            dst[2] = fmaf(x.z,a,c); dst[3] = fmaf(x.w,a,c);
            // V: per (group, channel) dequant; group constant within a 64-row tile
            int g = t >> 7;
            float4 xv = *reinterpret_cast<const float4*>(V + (size_t)t*rstride + boff + d4);
            float4 vs = *reinterpret_cast<const float4*>(VSCALE + (size_t)g*rstride + boff + d4);
            float4 vm = *reinterpret_cast<const float4*>(VMIN   + (size_t)g*rstride + boff + d4);
            float* dv = &vd[row*LSTR + d4];
            dv[0] = fmaf(xv.x, vs.x, vm.x); dv[1] = fmaf(xv.y, vs.y, vm.y);
            dv[2] = fmaf(xv.z, vs.z, vm.z); dv[3] = fmaf(xv.w, vs.w, vm.w);
        }
        __syncthreads();

        // recompute scores (identical order to phase 1)
        float sc[4][4];
        #pragma unroll
        for (int i=0;i<4;++i)
            #pragma unroll
            for (int j=0;j<4;++j) sc[i][j] = 0.0f;
        #pragma unroll 4
        for (int d = 0; d < HD; ++d) {
            float av[4], bv[4];
            #pragma unroll
            for (int i=0;i<4;++i) av[i] = qd[(4*ty+i)*LSTR + d];
            #pragma unroll
            for (int j=0;j<4;++j) bv[j] = kd[(4*tx+j)*LSTR + d];
            #pragma unroll
            for (int i=0;i<4;++i)
                #pragma unroll
                for (int j=0;j<4;++j)
                    sc[i][j] = fmaf(av[i], bv[j], sc[i][j]);
        }

        const bool dmask = (causal != 0) && (kt == qt);
        #pragma unroll
        for (int i=0;i<4;++i) {
            const int qrow = 4*ty + i;
            const int s = s0 + qrow;
            float mx = rs_max[qrow], invd = rs_invden[qrow];
            float pmn = rs_pmin[qrow], psc = rs_psc[qrow], ipsc = rs_ipsc[qrow];
            #pragma unroll
            for (int j=0;j<4;++j) {
                float sv   = sc[i][j]*SCALE;
                float prob = expf(sv - mx)*invd;
                float code = rintf((prob - pmn)*ipsc);   // half-even == jnp.round
                float pdv  = fmaf(code, psc, pmn);
                bool  msk  = dmask && (t0 + 4*tx + j > s);
                pdl[qrow*PSTR + 4*tx + j] = msk ? 0.0f : pdv;
            }
        }
        __syncthreads();

        // PV: acc[q][d] += pd[q][t] * vd[t][d];  d = tx + 16*jj (coalesced store)
        for (int t = 0; t < TK; ++t) {
            float pq[4], vv[8];
            #pragma unroll
            for (int i=0;i<4;++i)  pq[i]  = pdl[(4*ty+i)*PSTR + t];
            #pragma unroll
            for (int jj=0;jj<8;++jj) vv[jj] = vd[t*LSTR + tx + 16*jj];
            #pragma unroll
            for (int i=0;i<4;++i)
                #pragma unroll
                for (int jj=0;jj<8;++jj)
                    acc[i][jj] = fmaf(pq[i], vv[jj], acc[i][jj]);
        }
    }

    // epilogue: out[s][b][h*128 + d]
    #pragma unroll
    for (int i=0;i<4;++i) {
        int s = s0 + 4*ty + i;
        float* op = OUT + (size_t)s*rstride + boff;
        #pragma unroll
        for (int jj=0;jj<8;++jj) op[tx + 16*jj] = acc[i][jj];
    }
}

extern "C" void kernel_launch(void* const* d_in, const int* in_sizes, int n_in,
                              void* d_out, int out_size, void* d_ws, size_t ws_size,
                              hipStream_t stream) {
    (void)in_sizes; (void)n_in; (void)out_size; (void)d_ws; (void)ws_size;
    const float* Q   = (const float*)d_in[0];
    const float* K   = (const float*)d_in[1];
    const float* V   = (const float*)d_in[2];
    const float* QMN = (const float*)d_in[3];
    const float* QSC = (const float*)d_in[4];
    const float* KMN = (const float*)d_in[5];
    const float* KSC = (const float*)d_in[6];
    const float* VMN = (const float*)d_in[7];
    const float* VSC = (const float*)d_in[8];
    const int*   CS  = (const int*)d_in[9];
    float* out = (float*)d_out;

    dim3 grid((S_LEN/TQ) * BATCH * NH);   // 32 q-tiles * 32 (b,h) = 1024 blocks
    dim3 block(NTHREADS);
    hipLaunchKernelGGL(attn_q_kernel, grid, block, 0, stream,
                       Q, K, V, QMN, QSC, KMN, KSC, VMN, VSC, CS, out);
}

// Round 3
// 307.106 us; speedup vs baseline: 5.2128x; 5.2128x over previous
//
#include <hip/hip_runtime.h>
#include <math.h>

// Quantized causal attention on int8 MFMA.
// S=2048 B=2 H=16 D=128 G=16. Exact-integer reformulation:
//  QK:  score = ks*(qs*Sqk + qm*Sk8) + km*(qs*Sq8 + 128*qm)   [Sqk via mfma i8]
//  PV:  sum_t code*vd = vs*CV' + vm*C1' + (128*vs*GSV + 16384*vm) per 128-t group
//       with code' = code-128 (masked entries -> code 0 -> code' = -128, folded
//       into the precomputed group-sum term GSV).
// Pre-kernels build K8 (int8), V8T (int8 transposed), per-token sums, per-group
// V sums, and the full-row V-dequant sum (for the pmin term) in d_ws (~17 MB).
// R2 fix: prep_v transpose loop used d=idx>>4 (0..255!) / tg=idx&15 — OOB writes
// stomped GSV/SQs (-> inf via 128*vs*GSV) and left half of V8T unwritten.
// Correct: d=idx>>5 (0..127), tg=idx&31 (0..31).

#define S_LEN 2048
#define BATCH 2
#define NH    16
#define HD    128
#define RSTR  4096   // floats between seq positions
#define SCALE 0.08838834764831845f

typedef int v4i __attribute__((ext_vector_type(4)));
#define MFMA16(a,b,c) __builtin_amdgcn_mfma_i32_16x16x64_i8((a),(b),(c),0,0,0)

// ws byte offsets (total ~16.8 MB)
#define WS_K8   0u
#define WS_V8T  (8u*1024u*1024u)
#define WS_SQ   (16u*1024u*1024u)
#define WS_SK   (WS_SQ + 256u*1024u)
#define WS_GSV  (WS_SK + 256u*1024u)
#define WS_VSUM (WS_GSV + 256u*1024u)

// ---- pre-kernel 1: per-token sums for Q and K; pack K -> int8 ----
__global__ __launch_bounds__(256) void prep_sums(
    const float* __restrict__ Q, const float* __restrict__ K,
    signed char* __restrict__ K8, float* __restrict__ SQs, float* __restrict__ SKs)
{
    int idx = blockIdx.x*256 + threadIdx.x;   // 0 .. 65536*32-1
    int tensor = blockIdx.y;
    const float* src = tensor ? K : Q;
    int tau = idx >> 5, dg = idx & 31;
    float4 x = *(const float4*)(src + (size_t)tau*128 + 4*dg);
    float ssum = x.x + x.y + x.z + x.w;       // exact small-int sums
    #pragma unroll
    for (int off = 16; off >= 1; off >>= 1) ssum += __shfl_xor(ssum, off);
    if (tensor) {
        int a=(int)x.x, b2=(int)x.y, c=(int)x.z, d=(int)x.w;
        ((int*)K8)[(size_t)tau*32 + dg] = (a&255)|((b2&255)<<8)|((c&255)<<16)|((d&255)<<24);
        if ((threadIdx.x & 31) == 0) SKs[tau] = ssum;
    } else {
        if ((threadIdx.x & 31) == 0) SQs[tau] = ssum;
    }
}

// ---- pre-kernel 2: transpose V -> V8T[b,h,d,t] int8 ; per-group raw sums GSV ----
__global__ __launch_bounds__(256) void prep_v(
    const float* __restrict__ V, signed char* __restrict__ V8T, float* __restrict__ GSV)
{
    __shared__ signed char v8n[128*132];
    int tid = threadIdx.x;
    int bh = blockIdx.x & 31, ck = blockIdx.x >> 5;   // ck = 128-t chunk = v-group
    int b = bh >> 4, h = bh & 15;
    int t0 = ck * 128;
    int boff = b*2048 + h*128;
    #pragma unroll
    for (int it = 0; it < 16; ++it) {
        int idx = tid + it*256;
        int t = idx >> 5, d4 = (idx & 31) << 2;
        float4 x = *(const float4*)(V + (size_t)(t0+t)*RSTR + boff + d4);
        int a=(int)x.x, b2=(int)x.y, c=(int)x.z, d=(int)x.w;
        *(int*)(v8n + t*132 + d4) = (a&255)|((b2&255)<<8)|((c&255)<<16)|((d&255)<<24);
    }
    __syncthreads();
    if (tid < 128) {
        int acc = 0;
        for (int tt = 0; tt < 128; ++tt) acc += v8n[tt*132 + tid];
        GSV[((size_t)bh*16 + ck)*128 + tid] = (float)acc;
    }
    #pragma unroll
    for (int it = 0; it < 16; ++it) {
        int idx = tid + it*256;
        int d = idx >> 5, tg = idx & 31;   // R2 FIX: was idx>>4 / idx&15 (OOB)
        int p = (v8n[(4*tg+0)*132 + d]&255) | ((v8n[(4*tg+1)*132 + d]&255)<<8)
              | ((v8n[(4*tg+2)*132 + d]&255)<<16) | ((v8n[(4*tg+3)*132 + d]&255)<<24);
        *(int*)(V8T + ((size_t)bh*128 + d)*2048 + t0 + 4*tg) = p;
    }
}

// ---- pre-kernel 3: full-row dequant V sum (for pmin term) ----
__global__ __launch_bounds__(256) void prep_vsum(
    const float* __restrict__ GSV, const float* __restrict__ VSC,
    const float* __restrict__ VMN, float* __restrict__ VSUM)
{
    int idx = blockIdx.x*256 + threadIdx.x;   // 4096
    int bh = idx >> 7, d = idx & 127;
    int b = bh >> 4, h = bh & 15;
    float acc = 0.f;
    for (int g = 0; g < 16; ++g) {
        float gs = GSV[((size_t)bh*16 + g)*128 + d];
        int vi = ((g*BATCH + b)*NH + h)*HD + d;
        acc = fmaf(VSC[vi], gs, fmaf(128.0f, VMN[vi], acc));
    }
    VSUM[bh*128 + d] = acc;
}

// ---- main kernel ----
__global__ __launch_bounds__(256, 2) void attn_main(
    const float* __restrict__ Q,
    const signed char* __restrict__ K8, const signed char* __restrict__ V8T,
    const float* __restrict__ QMN, const float* __restrict__ QSC,
    const float* __restrict__ KMN, const float* __restrict__ KSC,
    const float* __restrict__ VMN, const float* __restrict__ VSC,
    const float* __restrict__ SQs, const float* __restrict__ SKs,
    const float* __restrict__ GSV, const float* __restrict__ VSUM,
    const int* __restrict__ CAUSAL, float* __restrict__ OUT)
{
    __shared__ __align__(16) signed char q8s[64*144];   // [q][d] int8
    __shared__ __align__(16) signed char k8s[128*144];  // [t][d] int8
    __shared__ __align__(16) signed char v8s[128*144];  // [d][t] int8 (transposed)
    __shared__ __align__(16) signed char pcs[64*144];   // [q][t] code' int8
    __shared__ float rs_c1[64], rs_c2[64], rs_c3[64];
    __shared__ float rs_mx[64], rs_den[64], rs_mn[64];
    __shared__ float rs_u1[64], rs_w1[64], rs_psc[64], rs_pmn[64];
    __shared__ float ktA[128], ktB[128], ktC[128];      // ks*SCALE, km*SCALE, sk8
    __shared__ float vsA[128], vsB[128], vsC[128];      // vs, vm, Bd

    const int tid  = threadIdx.x;
    const int w    = tid >> 6;
    const int lane = tid & 63;
    const int n    = lane & 15;
    const int quad = lane >> 4;
    const int bhi  = blockIdx.x & 31;
    const int qt   = 31 - (int)(blockIdx.x >> 5);   // heavy tiles first
    const int b    = bhi >> 4, h = bhi & 15;
    const int causal = *CAUSAL;
    const int s0   = qt * 64;
    const int boff = b*2048 + h*128;
    const v4i vzero = {0,0,0,0};
    const v4i ones  = {0x01010101,0x01010101,0x01010101,0x01010101};

    // ---- stage Q tile (float -> int8 LDS) + per-row consts ----
    #pragma unroll
    for (int it = 0; it < 8; ++it) {
        int idx = tid + it*256;
        int row = idx >> 5, d4 = (idx & 31) << 2;
        float4 x = *(const float4*)(Q + (size_t)(s0+row)*RSTR + boff + d4);
        int a=(int)x.x, b2=(int)x.y, c=(int)x.z, d=(int)x.w;
        *(int*)(q8s + row*144 + d4) = (a&255)|((b2&255)<<8)|((c&255)<<16)|((d&255)<<24);
    }
    if (tid < 64) {
        int si = (s0 + tid)*32 + bhi;
        float qs = QSC[si], qm = QMN[si];
        rs_c1[tid] = qs; rs_c2[tid] = qm;
        rs_c3[tid] = fmaf(qs, SQs[si], 128.0f*qm);
    }
    __syncthreads();

    const int kt_end = causal ? ((s0 + 63) >> 7) : 15;

    // hoisted phase-1 row data
    float c1r[4], c2r[4], c3r[4]; int qgr[4];
    #pragma unroll
    for (int r = 0; r < 4; ++r) {
        int qq = 16*w + 4*quad + r;
        c1r[r] = rs_c1[qq]; c2r[r] = rs_c2[qq]; c3r[r] = rs_c3[qq];
        qgr[r] = s0 + qq;
    }
    v4i a0p = *(const v4i*)(q8s + (16*w + n)*144 + 16*quad);
    v4i a1p = *(const v4i*)(q8s + (16*w + n)*144 + 64 + 16*quad);

    float m[4], l[4], mn[4];
    #pragma unroll
    for (int r = 0; r < 4; ++r) { m[r] = -INFINITY; l[r] = 0.f; mn[r] = INFINITY; }

    // ================= Phase 1: softmax stats =================
    for (int kt = 0; kt <= kt_end; ++kt) {
        const int t0g = kt * 128;
        __syncthreads();
        #pragma unroll
        for (int it = 0; it < 4; ++it) {
            int idx = tid + it*256;
            int trow = idx >> 3, doff = (idx & 7) << 4;
            uint4 x = *(const uint4*)(K8 + ((size_t)(t0g+trow)*32 + bhi)*128 + doff);
            *(uint4*)(k8s + trow*144 + doff) = x;
        }
        if (tid < 128) {
            int si = (t0g + tid)*32 + bhi;
            ktA[tid] = KSC[si]*SCALE; ktB[tid] = KMN[si]*SCALE; ktC[tid] = SKs[si];
        }
        __syncthreads();

        float tmax[4], tmin[4], sarr[8][4];
        #pragma unroll
        for (int r = 0; r < 4; ++r) { tmax[r] = -INFINITY; tmin[r] = INFINITY; }
        #pragma unroll
        for (int tb = 0; tb < 8; ++tb) {
            v4i b0 = *(const v4i*)(k8s + (16*tb + n)*144 + 16*quad);
            v4i b1 = *(const v4i*)(k8s + (16*tb + n)*144 + 64 + 16*quad);
            v4i acc = MFMA16(a0p, b0, vzero);
            acc = MFMA16(a1p, b1, acc);
            int tl = 16*tb + n, tg = t0g + tl;
            float ks = ktA[tl], km = ktB[tl], sk = ktC[tl];
            #pragma unroll
            for (int r = 0; r < 4; ++r) {
                float Sf = (float)acc[r];
                float sv = fmaf(ks, fmaf(c1r[r], Sf, c2r[r]*sk), km*c3r[r]);
                bool msk = causal && (tg > qgr[r]);
                sv = msk ? -INFINITY : sv;
                sarr[tb][r] = sv;
                tmax[r] = fmaxf(tmax[r], sv);
                tmin[r] = fminf(tmin[r], msk ? INFINITY : sv);
            }
        }
        #pragma unroll
        for (int r = 0; r < 4; ++r) {
            float mm = fmaxf(m[r], tmax[r]);
            if (mm > -INFINITY) {
                float a2 = l[r]*expf(m[r]-mm);
                #pragma unroll
                for (int tb = 0; tb < 8; ++tb) a2 += expf(sarr[tb][r]-mm);
                l[r] = a2; m[r] = mm;
            }
            mn[r] = fminf(mn[r], tmin[r]);
        }
    }

    // reduce stats across the 16 col-lanes
    #pragma unroll
    for (int r = 0; r < 4; ++r) {
        #pragma unroll
        for (int off = 1; off < 16; off <<= 1) {
            float m2 = __shfl_xor(m[r], off);
            float l2 = __shfl_xor(l[r], off);
            float n2 = __shfl_xor(mn[r], off);
            float mm = fmaxf(m[r], m2);
            if (mm > -INFINITY) l[r] = l[r]*expf(m[r]-mm) + l2*expf(m2-mm);
            m[r] = mm;
            mn[r] = fminf(mn[r], n2);
        }
        if (n == 0) {
            int qq = 16*w + 4*quad + r;
            rs_mx[qq] = m[r]; rs_den[qq] = l[r]; rs_mn[qq] = mn[r];
        }
    }
    __syncthreads();
    if (tid < 64) {
        float mx = rs_mx[tid], den = rs_den[tid], mnv = rs_mn[tid];
        float invd = 1.0f/den;
        int s = s0 + tid;
        bool hasmask = (causal != 0) && (s < S_LEN-1);
        float pmin = hasmask ? 0.0f : expf(mnv - mx)*invd;
        float psc  = (invd - pmin)/255.0f + 1e-12f;
        float ipsc = 1.0f/psc;
        rs_u1[tid] = invd*ipsc; rs_w1[tid] = -pmin*ipsc;
        rs_psc[tid] = psc; rs_pmn[tid] = pmin;
    }

    // ================= Phase 2: requant + PV =================
    float outa[4][8];
    #pragma unroll
    for (int r = 0; r < 4; ++r)
        #pragma unroll
        for (int db = 0; db < 8; ++db) outa[r][db] = 0.f;

    for (int kt = 0; kt <= kt_end; ++kt) {
        const int t0g = kt * 128;
        __syncthreads();
        #pragma unroll
        for (int it = 0; it < 4; ++it) {
            int idx = tid + it*256;
            int trow = idx >> 3, doff = (idx & 7) << 4;
            uint4 x = *(const uint4*)(K8 + ((size_t)(t0g+trow)*32 + bhi)*128 + doff);
            *(uint4*)(k8s + trow*144 + doff) = x;
            uint4 y = *(const uint4*)(V8T + ((size_t)bhi*128 + trow)*2048 + t0g + doff);
            *(uint4*)(v8s + trow*144 + doff) = y;
        }
        if (tid < 128) {
            int si = (t0g + tid)*32 + bhi;
            ktA[tid] = KSC[si]*SCALE; ktB[tid] = KMN[si]*SCALE; ktC[tid] = SKs[si];
        } else {
            int d = tid - 128;
            int vi = ((kt*BATCH + b)*NH + h)*HD + d;
            float vs = VSC[vi], vm = VMN[vi];
            float gs = GSV[((size_t)bhi*16 + kt)*128 + d];
            vsA[d] = vs; vsB[d] = vm;
            vsC[d] = fmaf(128.0f*vs, gs, 16384.0f*vm);
        }
        __syncthreads();

        // QK swapped (rows=t, cols=q) -> int8 codes in pcs[q][t]
        #pragma unroll
        for (int rb = 0; rb < 2; ++rb) {
            int trow = 32*w + 16*rb;
            v4i a0 = *(const v4i*)(k8s + (trow + n)*144 + 16*quad);
            v4i a1 = *(const v4i*)(k8s + (trow + n)*144 + 64 + 16*quad);
            float ksr[4], kmr[4], skr[4];
            int tgb = t0g + trow + 4*quad;
            #pragma unroll
            for (int r = 0; r < 4; ++r) {
                int tl = trow + 4*quad + r;
                ksr[r] = ktA[tl]; kmr[r] = ktB[tl]; skr[r] = ktC[tl];
            }
            #pragma unroll
            for (int cb = 0; cb < 4; ++cb) {
                v4i b0 = *(const v4i*)(q8s + (16*cb + n)*144 + 16*quad);
                v4i b1 = *(const v4i*)(q8s + (16*cb + n)*144 + 64 + 16*quad);
                v4i acc = MFMA16(a0, b0, vzero);
                acc = MFMA16(a1, b1, acc);
                int qcol = 16*cb + n, qg = s0 + qcol;
                float c1 = rs_c1[qcol], c2 = rs_c2[qcol], c3 = rs_c3[qcol];
                float mxq = rs_mx[qcol], u1 = rs_u1[qcol], w1 = rs_w1[qcol];
                int packed = 0;
                #pragma unroll
                for (int r = 0; r < 4; ++r) {
                    float Sf = (float)acc[r];
                    float sv = fmaf(ksr[r], fmaf(c1, Sf, c2*skr[r]), kmr[r]*c3);
                    bool msk = causal && (tgb + r > qg);
                    sv = msk ? -INFINITY : sv;
                    float e = expf(sv - mxq);
                    int ci = (int)rintf(fmaf(e, u1, w1)) - 128;
                    packed |= (ci & 255) << (8*r);
                }
                *(int*)(pcs + qcol*144 + trow + 4*quad) = packed;
            }
        }
        __syncthreads();

        // PV: CV' = codes x V8  (i8 MFMA), C1' via all-ones B
        {
            v4i a0 = *(const v4i*)(pcs + (16*w + n)*144 + 16*quad);
            v4i a1 = *(const v4i*)(pcs + (16*w + n)*144 + 64 + 16*quad);
            v4i c1a = MFMA16(a0, ones, vzero);
            c1a = MFMA16(a1, ones, c1a);
            float c1f[4];
            #pragma unroll
            for (int r = 0; r < 4; ++r) c1f[r] = (float)c1a[r];
            #pragma unroll
            for (int db = 0; db < 8; ++db) {
                v4i b0 = *(const v4i*)(v8s + (16*db + n)*144 + 16*quad);
                v4i b1 = *(const v4i*)(v8s + (16*db + n)*144 + 64 + 16*quad);
                v4i cv = MFMA16(a0, b0, vzero);
                cv = MFMA16(a1, b1, cv);
                int d = 16*db + n;
                float vs = vsA[d], vm = vsB[d], Bd = vsC[d];
                #pragma unroll
                for (int r = 0; r < 4; ++r)
                    outa[r][db] = fmaf(vs, (float)cv[r], fmaf(vm, c1f[r], outa[r][db] + Bd));
            }
        }
    }

    // ---- epilogue: out = psc*acc + pmin*Vsum ----
    float pscr[4], pmnr[4];
    #pragma unroll
    for (int r = 0; r < 4; ++r) {
        int qq = 16*w + 4*quad + r;
        pscr[r] = rs_psc[qq]; pmnr[r] = rs_pmn[qq];
    }
    #pragma unroll
    for (int db = 0; db < 8; ++db) {
        int d = 16*db + n;
        float vsum = VSUM[bhi*128 + d];
        #pragma unroll
        for (int r = 0; r < 4; ++r) {
            int s = s0 + 16*w + 4*quad + r;
            OUT[(size_t)s*RSTR + boff + d] = fmaf(pscr[r], outa[r][db], pmnr[r]*vsum);
        }
    }
}

extern "C" void kernel_launch(void* const* d_in, const int* in_sizes, int n_in,
                              void* d_out, int out_size, void* d_ws, size_t ws_size,
                              hipStream_t stream) {
    (void)in_sizes; (void)n_in; (void)out_size; (void)ws_size;
    const float* Q   = (const float*)d_in[0];
    const float* K   = (const float*)d_in[1];
    const float* V   = (const float*)d_in[2];
    const float* QMN = (const float*)d_in[3];
    const float* QSC = (const float*)d_in[4];
    const float* KMN = (const float*)d_in[5];
    const float* KSC = (const float*)d_in[6];
    const float* VMN = (const float*)d_in[7];
    const float* VSC = (const float*)d_in[8];
    const int*   CS  = (const int*)d_in[9];
    float* out = (float*)d_out;

    char* ws = (char*)d_ws;
    signed char* K8  = (signed char*)(ws + WS_K8);
    signed char* V8T = (signed char*)(ws + WS_V8T);
    float* SQs  = (float*)(ws + WS_SQ);
    float* SKs  = (float*)(ws + WS_SK);
    float* GSVp = (float*)(ws + WS_GSV);
    float* VSUM = (float*)(ws + WS_VSUM);

    prep_sums<<<dim3(8192, 2), 256, 0, stream>>>(Q, K, K8, SQs, SKs);
    prep_v<<<512, 256, 0, stream>>>(V, V8T, GSVp);
    prep_vsum<<<16, 256, 0, stream>>>(GSVp, VSC, VMN, VSUM);
    attn_main<<<1024, 256, 0, stream>>>(Q, K8, V8T, QMN, QSC, KMN, KSC, VMN, VSC,
                                        SQs, SKs, GSVp, VSUM, CS, out);
}

// Round 4
// 263.865 us; speedup vs baseline: 6.0670x; 1.1639x over previous
//
#include <hip/hip_runtime.h>
#include <math.h>

// Quantized causal attention on int8 MFMA — R4.
// R4 changes vs R3 (passed, 307us: main 181us VALU-bound 68%, preps ~126us):
//  1. exp2-domain softmax: scores carry SCALE/ln2; expf -> __builtin_amdgcn_exp2f
//     (1 quarter-rate v_exp_f32 instead of ~20-inst accurate expf).
//  2. Diagonal-tile split: only the last k-tile can be masked; non-diagonal
//     tiles skip the per-element cndmask (and min tracking drops its cndmask).
//  3. prep_v: register 4x4 byte-transpose via v_perm_b32 (8 perms / 16 bytes)
//     instead of 64+128 ds_read_u8 per thread; GSV via sext+shuffle reduce.

#define S_LEN 2048
#define BATCH 2
#define NH    16
#define HD    128
#define RSTR  4096   // floats between seq positions
#define SCALE2 (0.08838834764831845f * 1.4426950408889634f)   // (1/sqrt(128))/ln(2)
#define EXP2F(x) __builtin_amdgcn_exp2f(x)

typedef int v4i __attribute__((ext_vector_type(4)));
#define MFMA16(a,b,c) __builtin_amdgcn_mfma_i32_16x16x64_i8((a),(b),(c),0,0,0)

// ws byte offsets (total ~16.8 MB)
#define WS_K8   0u
#define WS_V8T  (8u*1024u*1024u)
#define WS_SQ   (16u*1024u*1024u)
#define WS_SK   (WS_SQ + 256u*1024u)
#define WS_GSV  (WS_SK + 256u*1024u)
#define WS_VSUM (WS_GSV + 256u*1024u)

// ---- pre-kernel 1: per-token sums for Q and K; pack K -> int8 ----
__global__ __launch_bounds__(256) void prep_sums(
    const float* __restrict__ Q, const float* __restrict__ K,
    signed char* __restrict__ K8, float* __restrict__ SQs, float* __restrict__ SKs)
{
    int idx = blockIdx.x*256 + threadIdx.x;
    int tensor = blockIdx.y;
    const float* src = tensor ? K : Q;
    int tau = idx >> 5, dg = idx & 31;
    float4 x = *(const float4*)(src + (size_t)tau*128 + 4*dg);
    float ssum = x.x + x.y + x.z + x.w;
    #pragma unroll
    for (int off = 16; off >= 1; off >>= 1) ssum += __shfl_xor(ssum, off);
    if (tensor) {
        int a=(int)x.x, b2=(int)x.y, c=(int)x.z, d=(int)x.w;
        ((int*)K8)[(size_t)tau*32 + dg] = (a&255)|((b2&255)<<8)|((c&255)<<16)|((d&255)<<24);
        if ((threadIdx.x & 31) == 0) SKs[tau] = ssum;
    } else {
        if ((threadIdx.x & 31) == 0) SQs[tau] = ssum;
    }
}

__device__ __forceinline__ int sbsum(unsigned p) {
    return (int)(signed char)(p) + (int)(signed char)(p>>8)
         + (int)(signed char)(p>>16) + (int)(signed char)(p>>24);
}

// ---- pre-kernel 2: V -> V8T[b,h,d,t] int8 via register byte-transpose ----
__global__ __launch_bounds__(256) void prep_v(
    const float* __restrict__ V, signed char* __restrict__ V8T, float* __restrict__ GSV)
{
    __shared__ int v8i[128*33];
    int tid = threadIdx.x;
    int bh = blockIdx.x & 31, ck = blockIdx.x >> 5;   // ck = 128-t chunk = v-group
    int b = bh >> 4, h = bh & 15;
    int t0 = ck * 128;
    int boff = b*2048 + h*128;
    #pragma unroll
    for (int it = 0; it < 16; ++it) {
        int idx = tid + it*256;
        int t = idx >> 5, dw = idx & 31;
        float4 x = *(const float4*)(V + (size_t)(t0+t)*RSTR + boff + 4*dw);
        int a=(int)x.x, b2=(int)x.y, c=(int)x.z, d=(int)x.w;
        v8i[t*33 + dw] = (a&255)|((b2&255)<<8)|((c&255)<<16)|((d&255)<<24);
    }
    __syncthreads();
    #pragma unroll
    for (int it = 0; it < 4; ++it) {
        int j = tid + it*256;
        int tg = j & 31, dw = j >> 5;   // tg: 4-row group, dw: d-word
        unsigned r0 = (unsigned)v8i[(4*tg+0)*33 + dw];
        unsigned r1 = (unsigned)v8i[(4*tg+1)*33 + dw];
        unsigned r2 = (unsigned)v8i[(4*tg+2)*33 + dw];
        unsigned r3 = (unsigned)v8i[(4*tg+3)*33 + dw];
        // 4x4 byte transpose: p_j = [r0.bj, r1.bj, r2.bj, r3.bj]
        unsigned x01 = __builtin_amdgcn_perm(r1, r0, 0x05010400u);
        unsigned x23 = __builtin_amdgcn_perm(r3, r2, 0x05010400u);
        unsigned y01 = __builtin_amdgcn_perm(r1, r0, 0x07030602u);
        unsigned y23 = __builtin_amdgcn_perm(r3, r2, 0x07030602u);
        unsigned p[4];
        p[0] = __builtin_amdgcn_perm(x23, x01, 0x05040100u);
        p[1] = __builtin_amdgcn_perm(x23, x01, 0x07060302u);
        p[2] = __builtin_amdgcn_perm(y23, y01, 0x05040100u);
        p[3] = __builtin_amdgcn_perm(y23, y01, 0x07060302u);
        int s[4];
        #pragma unroll
        for (int jj = 0; jj < 4; ++jj) {
            int d = 4*dw + jj;
            *(int*)(V8T + ((size_t)bh*128 + d)*2048 + t0 + 4*tg) = (int)p[jj];
            s[jj] = sbsum(p[jj]);
        }
        #pragma unroll
        for (int off = 1; off < 32; off <<= 1) {
            #pragma unroll
            for (int jj = 0; jj < 4; ++jj) s[jj] += __shfl_xor(s[jj], off);
        }
        if (tg == 0) {
            #pragma unroll
            for (int jj = 0; jj < 4; ++jj)
                GSV[((size_t)bh*16 + ck)*128 + 4*dw + jj] = (float)s[jj];
        }
    }
}

// ---- pre-kernel 3: full-row dequant V sum (for pmin term) ----
__global__ __launch_bounds__(256) void prep_vsum(
    const float* __restrict__ GSV, const float* __restrict__ VSC,
    const float* __restrict__ VMN, float* __restrict__ VSUM)
{
    int idx = blockIdx.x*256 + threadIdx.x;   // 4096
    int bh = idx >> 7, d = idx & 127;
    int b = bh >> 4, h = bh & 15;
    float acc = 0.f;
    for (int g = 0; g < 16; ++g) {
        float gs = GSV[((size_t)bh*16 + g)*128 + d];
        int vi = ((g*BATCH + b)*NH + h)*HD + d;
        acc = fmaf(VSC[vi], gs, fmaf(128.0f, VMN[vi], acc));
    }
    VSUM[bh*128 + d] = acc;
}

// ---- main kernel ----
__global__ __launch_bounds__(256, 2) void attn_main(
    const float* __restrict__ Q,
    const signed char* __restrict__ K8, const signed char* __restrict__ V8T,
    const float* __restrict__ QMN, const float* __restrict__ QSC,
    const float* __restrict__ KMN, const float* __restrict__ KSC,
    const float* __restrict__ VMN, const float* __restrict__ VSC,
    const float* __restrict__ SQs, const float* __restrict__ SKs,
    const float* __restrict__ GSV, const float* __restrict__ VSUM,
    const int* __restrict__ CAUSAL, float* __restrict__ OUT)
{
    __shared__ __align__(16) signed char q8s[64*144];   // [q][d] int8
    __shared__ __align__(16) signed char k8s[128*144];  // [t][d] int8
    __shared__ __align__(16) signed char v8s[128*144];  // [d][t] int8 (transposed)
    __shared__ __align__(16) signed char pcs[64*144];   // [q][t] code' int8
    __shared__ float rs_c1[64], rs_c2[64], rs_c3[64];
    __shared__ float rs_mx[64], rs_den[64], rs_mn[64];
    __shared__ float rs_u1[64], rs_w1[64], rs_psc[64], rs_pmn[64];
    __shared__ float ktA[128], ktB[128], ktC[128];      // ks*S2, km*S2, sk8
    __shared__ float vsA[128], vsB[128], vsC[128];      // vs, vm, Bd

    const int tid  = threadIdx.x;
    const int w    = tid >> 6;
    const int lane = tid & 63;
    const int n    = lane & 15;
    const int quad = lane >> 4;
    const int bhi  = blockIdx.x & 31;
    const int qt   = 31 - (int)(blockIdx.x >> 5);   // heavy tiles first
    const int b    = bhi >> 4, h = bhi & 15;
    const int causal = *CAUSAL;
    const int s0   = qt * 64;
    const int boff = b*2048 + h*128;
    const v4i vzero = {0,0,0,0};
    const v4i ones  = {0x01010101,0x01010101,0x01010101,0x01010101};

    // ---- stage Q tile (float -> int8 LDS) + per-row consts ----
    #pragma unroll
    for (int it = 0; it < 8; ++it) {
        int idx = tid + it*256;
        int row = idx >> 5, d4 = (idx & 31) << 2;
        float4 x = *(const float4*)(Q + (size_t)(s0+row)*RSTR + boff + d4);
        int a=(int)x.x, b2=(int)x.y, c=(int)x.z, d=(int)x.w;
        *(int*)(q8s + row*144 + d4) = (a&255)|((b2&255)<<8)|((c&255)<<16)|((d&255)<<24);
    }
    if (tid < 64) {
        int si = (s0 + tid)*32 + bhi;
        float qs = QSC[si], qm = QMN[si];
        rs_c1[tid] = qs; rs_c2[tid] = qm;
        rs_c3[tid] = fmaf(qs, SQs[si], 128.0f*qm);
    }
    __syncthreads();

    const int kt_end = causal ? ((s0 + 63) >> 7) : 15;

    float c1r[4], c2r[4], c3r[4]; int qgr[4];
    #pragma unroll
    for (int r = 0; r < 4; ++r) {
        int qq = 16*w + 4*quad + r;
        c1r[r] = rs_c1[qq]; c2r[r] = rs_c2[qq]; c3r[r] = rs_c3[qq];
        qgr[r] = s0 + qq;
    }
    v4i a0p = *(const v4i*)(q8s + (16*w + n)*144 + 16*quad);
    v4i a1p = *(const v4i*)(q8s + (16*w + n)*144 + 64 + 16*quad);

    float m[4], l[4], mn[4];
    #pragma unroll
    for (int r = 0; r < 4; ++r) { m[r] = -INFINITY; l[r] = 0.f; mn[r] = INFINITY; }

    // ================= Phase 1: softmax stats (log2 domain) =================
#define P1_TILE(MASKED)                                                          \
  do {                                                                           \
    const int t0g = kt * 128;                                                    \
    __syncthreads();                                                             \
    _Pragma("unroll")                                                            \
    for (int it = 0; it < 4; ++it) {                                             \
        int idx = tid + it*256;                                                  \
        int trow = idx >> 3, doff = (idx & 7) << 4;                              \
        *(uint4*)(k8s + trow*144 + doff) =                                       \
            *(const uint4*)(K8 + ((size_t)(t0g+trow)*32 + bhi)*128 + doff);      \
    }                                                                            \
    if (tid < 128) {                                                             \
        int si = (t0g + tid)*32 + bhi;                                           \
        ktA[tid] = KSC[si]*SCALE2; ktB[tid] = KMN[si]*SCALE2; ktC[tid] = SKs[si];\
    }                                                                            \
    __syncthreads();                                                             \
    float tmax[4], sarr[8][4];                                                   \
    _Pragma("unroll")                                                            \
    for (int r = 0; r < 4; ++r) tmax[r] = -INFINITY;                             \
    _Pragma("unroll")                                                            \
    for (int tb = 0; tb < 8; ++tb) {                                             \
        v4i b0 = *(const v4i*)(k8s + (16*tb + n)*144 + 16*quad);                 \
        v4i b1 = *(const v4i*)(k8s + (16*tb + n)*144 + 64 + 16*quad);            \
        v4i acc = MFMA16(a0p, b0, vzero);                                        \
        acc = MFMA16(a1p, b1, acc);                                              \
        int tl = 16*tb + n;                                                      \
        float ks = ktA[tl], km = ktB[tl], sk = ktC[tl];                          \
        _Pragma("unroll")                                                        \
        for (int r = 0; r < 4; ++r) {                                            \
            float Sf = (float)acc[r];                                            \
            float sv = fmaf(ks, fmaf(c1r[r], Sf, c2r[r]*sk), km*c3r[r]);         \
            if (MASKED) sv = (t0g + tl > qgr[r]) ? -INFINITY : sv;               \
            sarr[tb][r] = sv;                                                    \
            tmax[r] = fmaxf(tmax[r], sv);                                        \
            mn[r] = fminf(mn[r], sv);                                            \
        }                                                                        \
    }                                                                            \
    _Pragma("unroll")                                                            \
    for (int r = 0; r < 4; ++r) {                                                \
        float mm = fmaxf(m[r], tmax[r]);                                         \
        if (mm > -INFINITY) {                                                    \
            float a2 = l[r]*EXP2F(m[r]-mm);                                      \
            _Pragma("unroll")                                                    \
            for (int tb = 0; tb < 8; ++tb) a2 += EXP2F(sarr[tb][r]-mm);          \
            l[r] = a2; m[r] = mm;                                                \
        }                                                                        \
    }                                                                            \
  } while (0)

    {
        int kt;
        for (kt = 0; kt < kt_end; ++kt) P1_TILE(false);
        kt = kt_end;
        if (causal) P1_TILE(true); else P1_TILE(false);
    }

    // reduce stats across the 16 col-lanes
    #pragma unroll
    for (int r = 0; r < 4; ++r) {
        #pragma unroll
        for (int off = 1; off < 16; off <<= 1) {
            float m2 = __shfl_xor(m[r], off);
            float l2 = __shfl_xor(l[r], off);
            float n2 = __shfl_xor(mn[r], off);
            float mm = fmaxf(m[r], m2);
            if (mm > -INFINITY) l[r] = l[r]*EXP2F(m[r]-mm) + l2*EXP2F(m2-mm);
            m[r] = mm;
            mn[r] = fminf(mn[r], n2);
        }
        if (n == 0) {
            int qq = 16*w + 4*quad + r;
            rs_mx[qq] = m[r]; rs_den[qq] = l[r]; rs_mn[qq] = mn[r];
        }
    }
    __syncthreads();
    if (tid < 64) {
        float mx = rs_mx[tid], den = rs_den[tid], mnv = rs_mn[tid];
        float invd = 1.0f/den;
        int s = s0 + tid;
        bool hasmask = (causal != 0) && (s < S_LEN-1);
        float pmin = hasmask ? 0.0f : EXP2F(mnv - mx)*invd;
        float psc  = (invd - pmin)/255.0f + 1e-12f;
        float ipsc = 1.0f/psc;
        rs_u1[tid] = invd*ipsc; rs_w1[tid] = -pmin*ipsc;
        rs_psc[tid] = psc; rs_pmn[tid] = pmin;
    }

    // ================= Phase 2: requant + PV =================
    float outa[4][8];
    #pragma unroll
    for (int r = 0; r < 4; ++r)
        #pragma unroll
        for (int db = 0; db < 8; ++db) outa[r][db] = 0.f;

#define P2_TILE(MASKED)                                                          \
  do {                                                                           \
    const int t0g = kt * 128;                                                    \
    __syncthreads();                                                             \
    _Pragma("unroll")                                                            \
    for (int it = 0; it < 4; ++it) {                                             \
        int idx = tid + it*256;                                                  \
        int trow = idx >> 3, doff = (idx & 7) << 4;                              \
        *(uint4*)(k8s + trow*144 + doff) =                                       \
            *(const uint4*)(K8 + ((size_t)(t0g+trow)*32 + bhi)*128 + doff);      \
        *(uint4*)(v8s + trow*144 + doff) =                                       \
            *(const uint4*)(V8T + ((size_t)bhi*128 + trow)*2048 + t0g + doff);   \
    }                                                                            \
    if (tid < 128) {                                                             \
        int si = (t0g + tid)*32 + bhi;                                           \
        ktA[tid] = KSC[si]*SCALE2; ktB[tid] = KMN[si]*SCALE2; ktC[tid] = SKs[si];\
    } else {                                                                     \
        int d = tid - 128;                                                       \
        int vi = ((kt*BATCH + b)*NH + h)*HD + d;                                 \
        float vs = VSC[vi], vm = VMN[vi];                                        \
        float gs = GSV[((size_t)bhi*16 + kt)*128 + d];                           \
        vsA[d] = vs; vsB[d] = vm;                                                \
        vsC[d] = fmaf(128.0f*vs, gs, 16384.0f*vm);                               \
    }                                                                            \
    __syncthreads();                                                             \
    _Pragma("unroll")                                                            \
    for (int rb = 0; rb < 2; ++rb) {                                             \
        int trow = 32*w + 16*rb;                                                 \
        v4i a0 = *(const v4i*)(k8s + (trow + n)*144 + 16*quad);                  \
        v4i a1 = *(const v4i*)(k8s + (trow + n)*144 + 64 + 16*quad);             \
        float ksr[4], kmr[4], skr[4];                                            \
        int tgb = t0g + trow + 4*quad;                                           \
        _Pragma("unroll")                                                        \
        for (int r = 0; r < 4; ++r) {                                            \
            int tl = trow + 4*quad + r;                                          \
            ksr[r] = ktA[tl]; kmr[r] = ktB[tl]; skr[r] = ktC[tl];                \
        }                                                                        \
        _Pragma("unroll")                                                        \
        for (int cb = 0; cb < 4; ++cb) {                                         \
            v4i b0 = *(const v4i*)(q8s + (16*cb + n)*144 + 16*quad);             \
            v4i b1 = *(const v4i*)(q8s + (16*cb + n)*144 + 64 + 16*quad);        \
            v4i acc = MFMA16(a0, b0, vzero);                                     \
            acc = MFMA16(a1, b1, acc);                                           \
            int qcol = 16*cb + n, qg = s0 + qcol;                                \
            float c1 = rs_c1[qcol], c2 = rs_c2[qcol], c3 = rs_c3[qcol];          \
            float mxq = rs_mx[qcol], u1 = rs_u1[qcol], w1 = rs_w1[qcol];         \
            int packed = 0;                                                      \
            _Pragma("unroll")                                                    \
            for (int r = 0; r < 4; ++r) {                                        \
                float Sf = (float)acc[r];                                        \
                float x = fmaf(ksr[r], fmaf(c1, Sf, c2*skr[r]),                  \
                               fmaf(kmr[r], c3, -mxq));                          \
                if (MASKED) x = (tgb + r > qg) ? -INFINITY : x;                  \
                float e = EXP2F(x);                                              \
                int ci = (int)rintf(fmaf(e, u1, w1));                            \
                packed |= ci << (8*r);                                           \
            }                                                                    \
            packed ^= 0x80808080;  /* code - 128 per byte */                     \
            *(int*)(pcs + qcol*144 + trow + 4*quad) = packed;                    \
        }                                                                        \
    }                                                                            \
    __syncthreads();                                                             \
    {                                                                            \
        v4i a0 = *(const v4i*)(pcs + (16*w + n)*144 + 16*quad);                  \
        v4i a1 = *(const v4i*)(pcs + (16*w + n)*144 + 64 + 16*quad);             \
        v4i c1a = MFMA16(a0, ones, vzero);                                       \
        c1a = MFMA16(a1, ones, c1a);                                             \
        float c1f[4];                                                            \
        _Pragma("unroll")                                                        \
        for (int r = 0; r < 4; ++r) c1f[r] = (float)c1a[r];                      \
        _Pragma("unroll")                                                        \
        for (int db = 0; db < 8; ++db) {                                         \
            v4i b0 = *(const v4i*)(v8s + (16*db + n)*144 + 16*quad);             \
            v4i b1 = *(const v4i*)(v8s + (16*db + n)*144 + 64 + 16*quad);        \
            v4i cv = MFMA16(a0, b0, vzero);                                      \
            cv = MFMA16(a1, b1, cv);                                             \
            int d = 16*db + n;                                                   \
            float vs = vsA[d], vm = vsB[d], Bd = vsC[d];                         \
            _Pragma("unroll")                                                    \
            for (int r = 0; r < 4; ++r)                                          \
                outa[r][db] = fmaf(vs, (float)cv[r],                             \
                                   fmaf(vm, c1f[r], outa[r][db] + Bd));          \
        }                                                                        \
    }                                                                            \
  } while (0)

    {
        int kt;
        for (kt = 0; kt < kt_end; ++kt) P2_TILE(false);
        kt = kt_end;
        if (causal) P2_TILE(true); else P2_TILE(false);
    }

    // ---- epilogue: out = psc*acc + pmin*Vsum ----
    float pscr[4], pmnr[4];
    #pragma unroll
    for (int r = 0; r < 4; ++r) {
        int qq = 16*w + 4*quad + r;
        pscr[r] = rs_psc[qq]; pmnr[r] = rs_pmn[qq];
    }
    #pragma unroll
    for (int db = 0; db < 8; ++db) {
        int d = 16*db + n;
        float vsum = VSUM[bhi*128 + d];
        #pragma unroll
        for (int r = 0; r < 4; ++r) {
            int s = s0 + 16*w + 4*quad + r;
            OUT[(size_t)s*RSTR + boff + d] = fmaf(pscr[r], outa[r][db], pmnr[r]*vsum);
        }
    }
}

extern "C" void kernel_launch(void* const* d_in, const int* in_sizes, int n_in,
                              void* d_out, int out_size, void* d_ws, size_t ws_size,
                              hipStream_t stream) {
    (void)in_sizes; (void)n_in; (void)out_size; (void)ws_size;
    const float* Q   = (const float*)d_in[0];
    const float* K   = (const float*)d_in[1];
    const float* V   = (const float*)d_in[2];
    const float* QMN = (const float*)d_in[3];
    const float* QSC = (const float*)d_in[4];
    const float* KMN = (const float*)d_in[5];
    const float* KSC = (const float*)d_in[6];
    const float* VMN = (const float*)d_in[7];
    const float* VSC = (const float*)d_in[8];
    const int*   CS  = (const int*)d_in[9];
    float* out = (float*)d_out;

    char* ws = (char*)d_ws;
    signed char* K8  = (signed char*)(ws + WS_K8);
    signed char* V8T = (signed char*)(ws + WS_V8T);
    float* SQs  = (float*)(ws + WS_SQ);
    float* SKs  = (float*)(ws + WS_SK);
    float* GSVp = (float*)(ws + WS_GSV);
    float* VSUM = (float*)(ws + WS_VSUM);

    prep_sums<<<dim3(8192, 2), 256, 0, stream>>>(Q, K, K8, SQs, SKs);
    prep_v<<<512, 256, 0, stream>>>(V, V8T, GSVp);
    prep_vsum<<<16, 256, 0, stream>>>(GSVp, VSC, VMN, VSUM);
    attn_main<<<1024, 256, 0, stream>>>(Q, K8, V8T, QMN, QSC, KMN, KSC, VMN, VSC,
                                        SQs, SKs, GSVp, VSUM, CS, out);
}